// Round 1
// baseline (8395.015 us; speedup 1.0000x reference)
//
#include <hip/hip_runtime.h>
#include <hip/hip_bf16.h>
#include <math.h>

#define Bn 8
#define Tn 898
#define Dn 1024
#define Hn 16
#define DHn 64
#define Ln 12
#define FFn 4096
#define Vn 1024
#define BT (Bn*Tn)   /* 7184 */

typedef short bf16x8 __attribute__((ext_vector_type(8)));
typedef float f32x4 __attribute__((ext_vector_type(4)));

__device__ __forceinline__ ushort f2bf(float f) {
    union { float f; unsigned u; } c; c.f = f;
    unsigned r = c.u + 0x7fffu + ((c.u >> 16) & 1u);
    return (ushort)(r >> 16);
}

// ---------------- embedding + positional encoding ----------------
__global__ __launch_bounds__(256) void embed_kernel(
    const int* __restrict__ tids, const int* __restrict__ pids, const int* __restrict__ oids,
    const float* __restrict__ ttab, const float* __restrict__ ptab, const float* __restrict__ otab,
    const float* __restrict__ sep, float* __restrict__ x)
{
    int bp = blockIdx.x;
    int b = bp / Tn, pos = bp - b * Tn;
    int d0 = threadIdx.x * 4;
    float4 r;
    if (pos == 128 || pos == 385) {
        r = *(const float4*)(sep + d0);
    } else {
        int t; int id; const float* tab;
        if (pos < 128)      { t = pos;       id = tids[b*128 + t]; tab = ttab; }
        else if (pos < 385) { t = pos - 129; id = pids[b*256 + t]; tab = ptab; }
        else                { t = pos - 386; id = oids[b*512 + t]; tab = otab; }
        float4 e = *(const float4*)(tab + (size_t)id * Dn + d0);
        float pe[4];
        #pragma unroll
        for (int i = 0; i < 4; i++) {
            int d = d0 + i;
            int ii = d & 511;
            float omega = expf(-9.210340371976184f * (float)ii * (1.0f/512.0f));
            float ang = (float)t * omega;
            pe[i] = (d < 512) ? sinf(ang) : cosf(ang);
        }
        r.x = e.x + pe[0]; r.y = e.y + pe[1]; r.z = e.z + pe[2]; r.w = e.w + pe[3];
    }
    *(float4*)(x + (size_t)bp * Dn + d0) = r;
}

// ---------------- layernorm fp32 -> bf16 ----------------
__global__ __launch_bounds__(256) void ln_kernel(
    const float* __restrict__ x, const float* __restrict__ g, const float* __restrict__ bt,
    ushort* __restrict__ out)
{
    __shared__ float red[8];
    int row = blockIdx.x, tid = threadIdx.x;
    float4 v = ((const float4*)(x + (size_t)row * Dn))[tid];
    float s = v.x + v.y + v.z + v.w;
    #pragma unroll
    for (int o = 32; o; o >>= 1) s += __shfl_down(s, o);
    if ((tid & 63) == 0) red[tid >> 6] = s;
    __syncthreads();
    float mu = (red[0] + red[1] + red[2] + red[3]) * (1.0f / Dn);
    float d0 = v.x - mu, d1 = v.y - mu, d2 = v.z - mu, d3 = v.w - mu;
    float s2 = d0*d0 + d1*d1 + d2*d2 + d3*d3;
    #pragma unroll
    for (int o = 32; o; o >>= 1) s2 += __shfl_down(s2, o);
    if ((tid & 63) == 0) red[4 + (tid >> 6)] = s2;
    __syncthreads();
    float var = (red[4] + red[5] + red[6] + red[7]) * (1.0f / Dn);
    float rstd = rsqrtf(var + 1e-5f);
    float4 gg = ((const float4*)g)[tid];
    float4 bb = ((const float4*)bt)[tid];
    ushort4 o4;
    o4.x = f2bf(d0 * rstd * gg.x + bb.x);
    o4.y = f2bf(d1 * rstd * gg.y + bb.y);
    o4.z = f2bf(d2 * rstd * gg.z + bb.z);
    o4.w = f2bf(d3 * rstd * gg.w + bb.w);
    ((ushort4*)(out + (size_t)row * Dn))[tid] = o4;
}

// ---------------- GEMM: C = A(bf16, MxK) @ B(f32->bf16, KxN) [+bias][+resid][gelu] ----------------
// MODE 0: store bf16 (no bias)           -- qkv projection
// MODE 1: store f32 = resid + AB + bias  -- out proj / ff2 (residual update)
// MODE 2: store bf16 = gelu(AB + bias)   -- ff1
template<int MODE>
__global__ __launch_bounds__(256) void gemm_kernel(
    const ushort* __restrict__ A, const float* __restrict__ Bw,
    const float* __restrict__ bias, const float* __restrict__ resid,
    void* __restrict__ Cout, int M, int N, int K)
{
    __shared__ ushort Asm[128 * 40];
    __shared__ ushort Bsm[128 * 40];
    int tid = threadIdx.x;
    int lane = tid & 63, wave = tid >> 6;
    int wm = wave >> 1, wn = wave & 1;
    int m0 = blockIdx.y * 128, n0 = blockIdx.x * 128;
    int l16 = lane & 15, lhi = lane >> 4;

    f32x4 acc[4][4];
    #pragma unroll
    for (int i = 0; i < 4; i++)
        #pragma unroll
        for (int j = 0; j < 4; j++) acc[i][j] = (f32x4){0.f, 0.f, 0.f, 0.f};

    int arow = tid >> 1, acol = (tid & 1) * 16;
    int brow = tid >> 3, bcol = (tid & 7) * 16;
    const bool avalid = (m0 + arow) < M;
    const ushort* Aptr = A + (size_t)(m0 + arow) * K + acol;
    const float* Bptr = Bw + (size_t)brow * N + n0 + bcol;

    for (int kk = 0; kk < K; kk += 32) {
        uint4 a0 = make_uint4(0,0,0,0), a1 = make_uint4(0,0,0,0);
        if (avalid) {
            const uint4* p = (const uint4*)(Aptr + kk);
            a0 = p[0]; a1 = p[1];
        }
        const float4* qp = (const float4*)(Bptr + (size_t)kk * N);
        float4 f0 = qp[0], f1 = qp[1], f2 = qp[2], f3 = qp[3];
        ushort tb[16];
        tb[0]=f2bf(f0.x); tb[1]=f2bf(f0.y); tb[2]=f2bf(f0.z); tb[3]=f2bf(f0.w);
        tb[4]=f2bf(f1.x); tb[5]=f2bf(f1.y); tb[6]=f2bf(f1.z); tb[7]=f2bf(f1.w);
        tb[8]=f2bf(f2.x); tb[9]=f2bf(f2.y); tb[10]=f2bf(f2.z); tb[11]=f2bf(f2.w);
        tb[12]=f2bf(f3.x); tb[13]=f2bf(f3.y); tb[14]=f2bf(f3.z); tb[15]=f2bf(f3.w);

        __syncthreads();
        *(uint4*)&Asm[arow * 40 + acol] = a0;
        *(uint4*)&Asm[arow * 40 + acol + 8] = a1;
        #pragma unroll
        for (int i = 0; i < 16; i++) Bsm[(bcol + i) * 40 + brow] = tb[i];
        __syncthreads();

        bf16x8 af[4], bfr[4];
        #pragma unroll
        for (int mi = 0; mi < 4; mi++)
            af[mi] = *(const bf16x8*)&Asm[(wm*64 + mi*16 + l16) * 40 + lhi*8];
        #pragma unroll
        for (int ni = 0; ni < 4; ni++)
            bfr[ni] = *(const bf16x8*)&Bsm[(wn*64 + ni*16 + l16) * 40 + lhi*8];
        #pragma unroll
        for (int mi = 0; mi < 4; mi++)
            #pragma unroll
            for (int ni = 0; ni < 4; ni++)
                acc[mi][ni] = __builtin_amdgcn_mfma_f32_16x16x32_bf16(af[mi], bfr[ni], acc[mi][ni], 0, 0, 0);
    }

    #pragma unroll
    for (int mi = 0; mi < 4; mi++) {
        int rl = wm*64 + mi*16 + lhi*4;
        #pragma unroll
        for (int ni = 0; ni < 4; ni++) {
            int gcol = n0 + wn*64 + ni*16 + l16;
            float bs = (MODE == 0) ? 0.0f : bias[gcol];
            #pragma unroll
            for (int j = 0; j < 4; j++) {
                int grow = m0 + rl + j;
                if (grow >= M) continue;
                float v = acc[mi][ni][j] + bs;
                if (MODE == 1) {
                    float r = resid[(size_t)grow * N + gcol];
                    ((float*)Cout)[(size_t)grow * N + gcol] = r + v;
                } else if (MODE == 2) {
                    v = 0.5f * v * (1.0f + erff(v * 0.70710678118654752f));
                    ((ushort*)Cout)[(size_t)grow * N + gcol] = f2bf(v);
                } else {
                    ((ushort*)Cout)[(size_t)grow * N + gcol] = f2bf(v);
                }
            }
        }
    }
}

// ---------------- flash attention (causal), bf16 in/out ----------------
// grid: (qtiles=15, B, H), block 256 (4 waves; wave w owns q rows qt*64+w*16..+15)
__global__ __launch_bounds__(256) void attn_kernel(
    const ushort* __restrict__ qkv, ushort* __restrict__ out)
{
    __shared__ ushort Ksm[64 * 72];
    __shared__ ushort Vsm[64 * 72];
    __shared__ ushort Psm[4][16 * 72];
    int qt = blockIdx.x, b = blockIdx.y, h = blockIdx.z;
    int tid = threadIdx.x, lane = tid & 63, wave = tid >> 6;
    int l16 = lane & 15, lhi = lane >> 4;

    int qrow = qt*64 + wave*16 + l16;
    bf16x8 qf0 = {}, qf1 = {};
    if (qrow < Tn) {
        const ushort* qp = qkv + (size_t)(b*Tn + qrow) * 3072 + h*64 + lhi*8;
        qf0 = *(const bf16x8*)qp;
        qf1 = *(const bf16x8*)(qp + 32);
    }

    f32x4 o[4];
    #pragma unroll
    for (int i = 0; i < 4; i++) o[i] = (f32x4){0.f,0.f,0.f,0.f};
    float mrun[4] = {-1e30f,-1e30f,-1e30f,-1e30f};
    float sume[4] = {0.f,0.f,0.f,0.f};

    int kr = tid >> 2, cc = (tid & 3) * 16;
    const ushort* kvbase = qkv + (size_t)(b*Tn) * 3072 + h*64 + cc;
    int qg = qt*64 + wave*16 + lhi*4;

    for (int jt = 0; jt <= qt; jt++) {
        int kvr = jt*64 + kr;
        uint4 k0 = make_uint4(0,0,0,0), k1 = k0, v0 = k0, v1 = k0;
        if (kvr < Tn) {
            const ushort* p = kvbase + (size_t)kvr * 3072;
            k0 = *(const uint4*)(p + 1024);
            k1 = *(const uint4*)(p + 1024 + 8);
            v0 = *(const uint4*)(p + 2048);
            v1 = *(const uint4*)(p + 2048 + 8);
        }
        __syncthreads();
        *(uint4*)&Ksm[kr * 72 + cc] = k0;
        *(uint4*)&Ksm[kr * 72 + cc + 8] = k1;
        {
            ushort vv[16];
            *(uint4*)&vv[0] = v0; *(uint4*)&vv[8] = v1;
            #pragma unroll
            for (int i = 0; i < 16; i++) Vsm[(cc + i) * 72 + kr] = vv[i];
        }
        __syncthreads();

        f32x4 s[4];
        #pragma unroll
        for (int ni = 0; ni < 4; ni++) {
            s[ni] = (f32x4){0.f,0.f,0.f,0.f};
            bf16x8 kf0 = *(const bf16x8*)&Ksm[(ni*16 + l16) * 72 + lhi*8];
            bf16x8 kf1 = *(const bf16x8*)&Ksm[(ni*16 + l16) * 72 + lhi*8 + 32];
            s[ni] = __builtin_amdgcn_mfma_f32_16x16x32_bf16(qf0, kf0, s[ni], 0, 0, 0);
            s[ni] = __builtin_amdgcn_mfma_f32_16x16x32_bf16(qf1, kf1, s[ni], 0, 0, 0);
        }

        float pv[4][4];
        #pragma unroll
        for (int j = 0; j < 4; j++) {
            int qgj = qg + j;
            float mx = -1e30f;
            #pragma unroll
            for (int ni = 0; ni < 4; ni++) {
                int kvg = jt*64 + ni*16 + l16;
                float e = (kvg <= qgj && kvg < Tn) ? s[ni][j] * 0.125f : -1e30f;
                pv[ni][j] = e;
                mx = fmaxf(mx, e);
            }
            #pragma unroll
            for (int m = 1; m < 16; m <<= 1) mx = fmaxf(mx, __shfl_xor(mx, m));
            float mnew = fmaxf(mrun[j], mx);
            float fac = expf(mrun[j] - mnew);
            mrun[j] = mnew;
            float rs = 0.f;
            #pragma unroll
            for (int ni = 0; ni < 4; ni++) { pv[ni][j] = expf(pv[ni][j] - mnew); rs += pv[ni][j]; }
            #pragma unroll
            for (int m = 1; m < 16; m <<= 1) rs += __shfl_xor(rs, m);
            sume[j] = sume[j] * fac + rs;
            #pragma unroll
            for (int di = 0; di < 4; di++) o[di][j] *= fac;
        }

        #pragma unroll
        for (int j = 0; j < 4; j++)
            #pragma unroll
            for (int ni = 0; ni < 4; ni++)
                Psm[wave][(lhi*4 + j) * 72 + ni*16 + l16] = f2bf(pv[ni][j]);
        __syncthreads();

        bf16x8 pf0 = *(const bf16x8*)&Psm[wave][l16 * 72 + lhi*8];
        bf16x8 pf1 = *(const bf16x8*)&Psm[wave][l16 * 72 + lhi*8 + 32];
        #pragma unroll
        for (int di = 0; di < 4; di++) {
            bf16x8 vf0 = *(const bf16x8*)&Vsm[(di*16 + l16) * 72 + lhi*8];
            bf16x8 vf1 = *(const bf16x8*)&Vsm[(di*16 + l16) * 72 + lhi*8 + 32];
            o[di] = __builtin_amdgcn_mfma_f32_16x16x32_bf16(pf0, vf0, o[di], 0, 0, 0);
            o[di] = __builtin_amdgcn_mfma_f32_16x16x32_bf16(pf1, vf1, o[di], 0, 0, 0);
        }
    }

    #pragma unroll
    for (int j = 0; j < 4; j++) {
        int qgj = qg + j;
        if (qgj >= Tn) continue;
        float inv = 1.0f / sume[j];
        #pragma unroll
        for (int di = 0; di < 4; di++)
            out[(size_t)(b*Tn + qgj) * Dn + h*64 + di*16 + l16] = f2bf(o[di][j] * inv);
    }
}

// ---------------- final fc on last position ----------------
__global__ __launch_bounds__(256) void fc_kernel(
    const float* __restrict__ x, const float* __restrict__ w,
    const float* __restrict__ bias, float* __restrict__ out)
{
    __shared__ float xs[Dn];
    int b = blockIdx.y;
    int v = blockIdx.x * 256 + threadIdx.x;
    float4 t = ((const float4*)(x + (size_t)(b*Tn + Tn - 1) * Dn))[threadIdx.x];
    ((float4*)xs)[threadIdx.x] = t;
    __syncthreads();
    float acc = bias[v];
    for (int d = 0; d < Dn; d++)
        acc = fmaf(xs[d], w[(size_t)d * Vn + v], acc);
    out[(size_t)b * Vn + v] = acc;
}

extern "C" void kernel_launch(void* const* d_in, const int* in_sizes, int n_in,
                              void* d_out, int out_size, void* d_ws, size_t ws_size,
                              hipStream_t stream)
{
    const int*   text_ids  = (const int*)d_in[0];
    const int*   prompt_ids= (const int*)d_in[1];
    const int*   output_ids= (const int*)d_in[2];
    const float* text_tab  = (const float*)d_in[3];
    const float* prompt_tab= (const float*)d_in[4];
    const float* output_tab= (const float*)d_in[5];
    const float* sep       = (const float*)d_in[6];
    const float* ln1_g     = (const float*)d_in[7];
    const float* ln1_b     = (const float*)d_in[8];
    const float* qkv_w     = (const float*)d_in[9];
    const float* out_w     = (const float*)d_in[10];
    const float* out_b     = (const float*)d_in[11];
    const float* ln2_g     = (const float*)d_in[12];
    const float* ln2_b     = (const float*)d_in[13];
    const float* ff1_w     = (const float*)d_in[14];
    const float* ff1_b     = (const float*)d_in[15];
    const float* ff2_w     = (const float*)d_in[16];
    const float* ff2_b     = (const float*)d_in[17];
    const float* fc_w      = (const float*)d_in[18];
    const float* fc_b      = (const float*)d_in[19];

    char* ws = (char*)d_ws;
    float*  x    = (float*)(ws);                               // BT*Dn*4   = 29,425,664
    ushort* h    = (ushort*)(ws + 29425664);                   // BT*Dn*2   = 14,712,832
    ushort* qkv  = (ushort*)(ws + 44138496);                   // BT*3Dn*2  = 44,138,496
    ushort* attn = (ushort*)(ws + 88276992);                   // BT*Dn*2   = 14,712,832
    ushort* ff1o = (ushort*)(ws + 102989824);                  // BT*FFn*2  = 58,851,328

    embed_kernel<<<BT, 256, 0, stream>>>(text_ids, prompt_ids, output_ids,
                                         text_tab, prompt_tab, output_tab, sep, x);

    const int MT = 57; // ceil(7184/128)
    for (int l = 0; l < Ln; l++) {
        ln_kernel<<<BT, 256, 0, stream>>>(x, ln1_g + l*Dn, ln1_b + l*Dn, h);
        gemm_kernel<0><<<dim3(3*Dn/128, MT), 256, 0, stream>>>(
            h, qkv_w + (size_t)l*Dn*3*Dn, nullptr, nullptr, qkv, BT, 3*Dn, Dn);
        attn_kernel<<<dim3(15, Bn, Hn), 256, 0, stream>>>(qkv, attn);
        gemm_kernel<1><<<dim3(Dn/128, MT), 256, 0, stream>>>(
            attn, out_w + (size_t)l*Dn*Dn, out_b + l*Dn, x, x, BT, Dn, Dn);
        ln_kernel<<<BT, 256, 0, stream>>>(x, ln2_g + l*Dn, ln2_b + l*Dn, h);
        gemm_kernel<2><<<dim3(FFn/128, MT), 256, 0, stream>>>(
            h, ff1_w + (size_t)l*Dn*FFn, ff1_b + l*FFn, nullptr, ff1o, BT, FFn, Dn);
        gemm_kernel<1><<<dim3(Dn/128, MT), 256, 0, stream>>>(
            ff1o, ff2_w + (size_t)l*FFn*Dn, ff2_b + l*Dn, x, x, BT, Dn, FFn);
    }

    fc_kernel<<<dim3(Vn/256, Bn), 256, 0, stream>>>(x, fc_w, fc_b, (float*)d_out);
}

// Round 2
// 5908.285 us; speedup vs baseline: 1.4209x; 1.4209x over previous
//
#include <hip/hip_runtime.h>
#include <hip/hip_bf16.h>
#include <math.h>

#define Bn 8
#define Tn 898
#define Dn 1024
#define Hn 16
#define DHn 64
#define Ln 12
#define FFn 4096
#define Vn 1024
#define BT (Bn*Tn)   /* 7184 */

typedef short bf16x8 __attribute__((ext_vector_type(8)));
typedef float f32x4 __attribute__((ext_vector_type(4)));

__device__ __forceinline__ ushort f2bf(float f) {
    union { float f; unsigned u; } c; c.f = f;
    unsigned r = c.u + 0x7fffu + ((c.u >> 16) & 1u);
    return (ushort)(r >> 16);
}

__device__ __forceinline__ void glds16(const void* g, void* l) {
    __builtin_amdgcn_global_load_lds(
        (const __attribute__((address_space(1))) unsigned int*)g,
        (__attribute__((address_space(3))) unsigned int*)l, 16, 0, 0);
}

// ---------------- weight transpose + cast: f32 [K][N] -> bf16 [N][K] ----------------
__global__ __launch_bounds__(256) void transpose_cast_kernel(
    const float* __restrict__ in, ushort* __restrict__ out,
    int K, int N, size_t in_ls, size_t out_ls)
{
    __shared__ ushort t[64][68];
    const float* inp = in + (size_t)blockIdx.z * in_ls;
    ushort* outp = out + (size_t)blockIdx.z * out_ls;
    int n0 = blockIdx.x * 64, k0 = blockIdx.y * 64;
    int tx = threadIdx.x & 63, ty = threadIdx.x >> 6;
    #pragma unroll
    for (int p = 0; p < 16; p++) {
        int kl = p * 4 + ty;
        t[tx][kl] = f2bf(inp[(size_t)(k0 + kl) * N + n0 + tx]);
    }
    __syncthreads();
    int tx4 = threadIdx.x & 15, ty4 = threadIdx.x >> 4;  // 16 rows/pass, 4 passes
    #pragma unroll
    for (int p = 0; p < 4; p++) {
        int nl = p * 16 + ty4;
        ushort4 v;
        v.x = t[nl][4*tx4]; v.y = t[nl][4*tx4+1]; v.z = t[nl][4*tx4+2]; v.w = t[nl][4*tx4+3];
        *(ushort4*)&outp[(size_t)(n0 + nl) * K + k0 + 4*tx4] = v;
    }
}

// ---------------- embedding + positional encoding ----------------
__global__ __launch_bounds__(256) void embed_kernel(
    const int* __restrict__ tids, const int* __restrict__ pids, const int* __restrict__ oids,
    const float* __restrict__ ttab, const float* __restrict__ ptab, const float* __restrict__ otab,
    const float* __restrict__ sep, float* __restrict__ x)
{
    int bp = blockIdx.x;
    int b = bp / Tn, pos = bp - b * Tn;
    int d0 = threadIdx.x * 4;
    float4 r;
    if (pos == 128 || pos == 385) {
        r = *(const float4*)(sep + d0);
    } else {
        int t; int id; const float* tab;
        if (pos < 128)      { t = pos;       id = tids[b*128 + t]; tab = ttab; }
        else if (pos < 385) { t = pos - 129; id = pids[b*256 + t]; tab = ptab; }
        else                { t = pos - 386; id = oids[b*512 + t]; tab = otab; }
        float4 e = *(const float4*)(tab + (size_t)id * Dn + d0);
        float pe[4];
        #pragma unroll
        for (int i = 0; i < 4; i++) {
            int d = d0 + i;
            int ii = d & 511;
            float omega = expf(-9.210340371976184f * (float)ii * (1.0f/512.0f));
            float ang = (float)t * omega;
            pe[i] = (d < 512) ? sinf(ang) : cosf(ang);
        }
        r.x = e.x + pe[0]; r.y = e.y + pe[1]; r.z = e.z + pe[2]; r.w = e.w + pe[3];
    }
    *(float4*)(x + (size_t)bp * Dn + d0) = r;
}

// ---------------- layernorm fp32 -> bf16 ----------------
__global__ __launch_bounds__(256) void ln_kernel(
    const float* __restrict__ x, const float* __restrict__ g, const float* __restrict__ bt,
    ushort* __restrict__ out)
{
    __shared__ float red[8];
    int row = blockIdx.x, tid = threadIdx.x;
    float4 v = ((const float4*)(x + (size_t)row * Dn))[tid];
    float s = v.x + v.y + v.z + v.w;
    #pragma unroll
    for (int o = 32; o; o >>= 1) s += __shfl_down(s, o);
    if ((tid & 63) == 0) red[tid >> 6] = s;
    __syncthreads();
    float mu = (red[0] + red[1] + red[2] + red[3]) * (1.0f / Dn);
    float d0 = v.x - mu, d1 = v.y - mu, d2 = v.z - mu, d3 = v.w - mu;
    float s2 = d0*d0 + d1*d1 + d2*d2 + d3*d3;
    #pragma unroll
    for (int o = 32; o; o >>= 1) s2 += __shfl_down(s2, o);
    if ((tid & 63) == 0) red[4 + (tid >> 6)] = s2;
    __syncthreads();
    float var = (red[4] + red[5] + red[6] + red[7]) * (1.0f / Dn);
    float rstd = rsqrtf(var + 1e-5f);
    float4 gg = ((const float4*)g)[tid];
    float4 bb = ((const float4*)bt)[tid];
    ushort4 o4;
    o4.x = f2bf(d0 * rstd * gg.x + bb.x);
    o4.y = f2bf(d1 * rstd * gg.y + bb.y);
    o4.z = f2bf(d2 * rstd * gg.z + bb.z);
    o4.w = f2bf(d3 * rstd * gg.w + bb.w);
    ((ushort4*)(out + (size_t)row * Dn))[tid] = o4;
}

// ---------------- GEMM m97-style: C = A(bf16 [M][K]) @ Bw(bf16 [N][K])^T ----------------
// MODE 0: store bf16 (no bias)           -- qkv projection
// MODE 1: store f32 = resid + AB + bias  -- out proj / ff2 (residual update)
// MODE 2: store bf16 = gelu(AB + bias)   -- ff1
template<int MODE>
__global__ __launch_bounds__(256) void gemm_kernel(
    const ushort* __restrict__ A, const ushort* __restrict__ Bw,
    const float* __restrict__ bias, const float* __restrict__ resid,
    void* __restrict__ Cout, int M, int N, int K)
{
    __shared__ ushort Asm[128 * 32];
    __shared__ ushort Bsm[128 * 32];
    int tid = threadIdx.x;
    int lane = tid & 63, wv = tid >> 6;
    int wm = wv >> 1, wn = wv & 1;
    int m0 = blockIdx.y * 128, n0 = blockIdx.x * 128;
    int l16 = lane & 15, lhi = lane >> 4;

    f32x4 acc[4][4];
    #pragma unroll
    for (int i = 0; i < 4; i++)
        #pragma unroll
        for (int j = 0; j < 4; j++) acc[i][j] = (f32x4){0.f, 0.f, 0.f, 0.f};

    // staging: thread t covers LDS elem (wv*512 + lane*8) of each 2048-elem half-tile
    int srow = wv * 16 + (lane >> 2);
    int skc  = (lane & 3) * 8;
    const ushort* Ap0 = A  + (size_t)(m0 + srow) * K + skc;
    const ushort* Ap1 = A  + (size_t)(m0 + 64 + srow) * K + skc;
    const ushort* Bp0 = Bw + (size_t)(n0 + srow) * K + skc;
    const ushort* Bp1 = Bw + (size_t)(n0 + 64 + srow) * K + skc;
    ushort* ldsA0 = &Asm[wv * 512];
    ushort* ldsA1 = &Asm[2048 + wv * 512];
    ushort* ldsB0 = &Bsm[wv * 512];
    ushort* ldsB1 = &Bsm[2048 + wv * 512];

    for (int kk = 0; kk < K; kk += 32) {
        __syncthreads();
        glds16(Ap0 + kk, ldsA0);
        glds16(Ap1 + kk, ldsA1);
        glds16(Bp0 + kk, ldsB0);
        glds16(Bp1 + kk, ldsB1);
        __syncthreads();

        bf16x8 af[4], bfr[4];
        #pragma unroll
        for (int mi = 0; mi < 4; mi++)
            af[mi] = *(const bf16x8*)&Asm[(wm*64 + mi*16 + l16) * 32 + lhi*8];
        #pragma unroll
        for (int ni = 0; ni < 4; ni++)
            bfr[ni] = *(const bf16x8*)&Bsm[(wn*64 + ni*16 + l16) * 32 + lhi*8];
        #pragma unroll
        for (int mi = 0; mi < 4; mi++)
            #pragma unroll
            for (int ni = 0; ni < 4; ni++)
                acc[mi][ni] = __builtin_amdgcn_mfma_f32_16x16x32_bf16(af[mi], bfr[ni], acc[mi][ni], 0, 0, 0);
    }

    #pragma unroll
    for (int mi = 0; mi < 4; mi++) {
        int rl = wm*64 + mi*16 + lhi*4;
        #pragma unroll
        for (int ni = 0; ni < 4; ni++) {
            int gcol = n0 + wn*64 + ni*16 + l16;
            float bs = (MODE == 0) ? 0.0f : bias[gcol];
            #pragma unroll
            for (int j = 0; j < 4; j++) {
                int grow = m0 + rl + j;
                if (grow >= M) continue;
                float v = acc[mi][ni][j] + bs;
                if (MODE == 1) {
                    float r = resid[(size_t)grow * N + gcol];
                    ((float*)Cout)[(size_t)grow * N + gcol] = r + v;
                } else if (MODE == 2) {
                    v = 0.5f * v * (1.0f + erff(v * 0.70710678118654752f));
                    ((ushort*)Cout)[(size_t)grow * N + gcol] = f2bf(v);
                } else {
                    ((ushort*)Cout)[(size_t)grow * N + gcol] = f2bf(v);
                }
            }
        }
    }
}

// ---------------- flash attention (causal), bf16 in/out ----------------
__global__ __launch_bounds__(256) void attn_kernel(
    const ushort* __restrict__ qkv, ushort* __restrict__ out)
{
    __shared__ ushort Ksm[64 * 72];
    __shared__ ushort Vsm[64 * 72];
    __shared__ ushort Psm[4][16 * 72];
    int qt = blockIdx.x, b = blockIdx.y, h = blockIdx.z;
    int tid = threadIdx.x, lane = tid & 63, wave = tid >> 6;
    int l16 = lane & 15, lhi = lane >> 4;

    int qrow = qt*64 + wave*16 + l16;
    bf16x8 qf0 = {}, qf1 = {};
    if (qrow < Tn) {
        const ushort* qp = qkv + (size_t)(b*Tn + qrow) * 3072 + h*64 + lhi*8;
        qf0 = *(const bf16x8*)qp;
        qf1 = *(const bf16x8*)(qp + 32);
    }

    f32x4 o[4];
    #pragma unroll
    for (int i = 0; i < 4; i++) o[i] = (f32x4){0.f,0.f,0.f,0.f};
    float mrun[4] = {-1e30f,-1e30f,-1e30f,-1e30f};
    float sume[4] = {0.f,0.f,0.f,0.f};

    int kr = tid >> 2, cc = (tid & 3) * 16;
    const ushort* kvbase = qkv + (size_t)(b*Tn) * 3072 + h*64 + cc;
    int qg = qt*64 + wave*16 + lhi*4;

    for (int jt = 0; jt <= qt; jt++) {
        int kvr = jt*64 + kr;
        uint4 k0 = make_uint4(0,0,0,0), k1 = k0, v0 = k0, v1 = k0;
        if (kvr < Tn) {
            const ushort* p = kvbase + (size_t)kvr * 3072;
            k0 = *(const uint4*)(p + 1024);
            k1 = *(const uint4*)(p + 1024 + 8);
            v0 = *(const uint4*)(p + 2048);
            v1 = *(const uint4*)(p + 2048 + 8);
        }
        __syncthreads();
        *(uint4*)&Ksm[kr * 72 + cc] = k0;
        *(uint4*)&Ksm[kr * 72 + cc + 8] = k1;
        {
            ushort vv[16];
            *(uint4*)&vv[0] = v0; *(uint4*)&vv[8] = v1;
            #pragma unroll
            for (int i = 0; i < 16; i++) Vsm[(cc + i) * 72 + kr] = vv[i];
        }
        __syncthreads();

        f32x4 s[4];
        #pragma unroll
        for (int ni = 0; ni < 4; ni++) {
            s[ni] = (f32x4){0.f,0.f,0.f,0.f};
            bf16x8 kf0 = *(const bf16x8*)&Ksm[(ni*16 + l16) * 72 + lhi*8];
            bf16x8 kf1 = *(const bf16x8*)&Ksm[(ni*16 + l16) * 72 + lhi*8 + 32];
            s[ni] = __builtin_amdgcn_mfma_f32_16x16x32_bf16(qf0, kf0, s[ni], 0, 0, 0);
            s[ni] = __builtin_amdgcn_mfma_f32_16x16x32_bf16(qf1, kf1, s[ni], 0, 0, 0);
        }

        float pv[4][4];
        #pragma unroll
        for (int j = 0; j < 4; j++) {
            int qgj = qg + j;
            float mx = -1e30f;
            #pragma unroll
            for (int ni = 0; ni < 4; ni++) {
                int kvg = jt*64 + ni*16 + l16;
                float e = (kvg <= qgj && kvg < Tn) ? s[ni][j] * 0.125f : -1e30f;
                pv[ni][j] = e;
                mx = fmaxf(mx, e);
            }
            #pragma unroll
            for (int m = 1; m < 16; m <<= 1) mx = fmaxf(mx, __shfl_xor(mx, m));
            float mnew = fmaxf(mrun[j], mx);
            float fac = expf(mrun[j] - mnew);
            mrun[j] = mnew;
            float rs = 0.f;
            #pragma unroll
            for (int ni = 0; ni < 4; ni++) { pv[ni][j] = expf(pv[ni][j] - mnew); rs += pv[ni][j]; }
            #pragma unroll
            for (int m = 1; m < 16; m <<= 1) rs += __shfl_xor(rs, m);
            sume[j] = sume[j] * fac + rs;
            #pragma unroll
            for (int di = 0; di < 4; di++) o[di][j] *= fac;
        }

        #pragma unroll
        for (int j = 0; j < 4; j++)
            #pragma unroll
            for (int ni = 0; ni < 4; ni++)
                Psm[wave][(lhi*4 + j) * 72 + ni*16 + l16] = f2bf(pv[ni][j]);
        __syncthreads();

        bf16x8 pf0 = *(const bf16x8*)&Psm[wave][l16 * 72 + lhi*8];
        bf16x8 pf1 = *(const bf16x8*)&Psm[wave][l16 * 72 + lhi*8 + 32];
        #pragma unroll
        for (int di = 0; di < 4; di++) {
            bf16x8 vf0 = *(const bf16x8*)&Vsm[(di*16 + l16) * 72 + lhi*8];
            bf16x8 vf1 = *(const bf16x8*)&Vsm[(di*16 + l16) * 72 + lhi*8 + 32];
            o[di] = __builtin_amdgcn_mfma_f32_16x16x32_bf16(pf0, vf0, o[di], 0, 0, 0);
            o[di] = __builtin_amdgcn_mfma_f32_16x16x32_bf16(pf1, vf1, o[di], 0, 0, 0);
        }
    }

    #pragma unroll
    for (int j = 0; j < 4; j++) {
        int qgj = qg + j;
        if (qgj >= Tn) continue;
        float inv = 1.0f / sume[j];
        #pragma unroll
        for (int di = 0; di < 4; di++)
            out[(size_t)(b*Tn + qgj) * Dn + h*64 + di*16 + l16] = f2bf(o[di][j] * inv);
    }
}

// ---------------- final fc on last position ----------------
__global__ __launch_bounds__(256) void fc_kernel(
    const float* __restrict__ x, const float* __restrict__ w,
    const float* __restrict__ bias, float* __restrict__ out)
{
    __shared__ float xs[Dn];
    int b = blockIdx.y;
    int v = blockIdx.x * 256 + threadIdx.x;
    float4 t = ((const float4*)(x + (size_t)(b*Tn + Tn - 1) * Dn))[threadIdx.x];
    ((float4*)xs)[threadIdx.x] = t;
    __syncthreads();
    float acc = bias[v];
    for (int d = 0; d < Dn; d++)
        acc = fmaf(xs[d], w[(size_t)d * Vn + v], acc);
    out[(size_t)b * Vn + v] = acc;
}

extern "C" void kernel_launch(void* const* d_in, const int* in_sizes, int n_in,
                              void* d_out, int out_size, void* d_ws, size_t ws_size,
                              hipStream_t stream)
{
    const int*   text_ids  = (const int*)d_in[0];
    const int*   prompt_ids= (const int*)d_in[1];
    const int*   output_ids= (const int*)d_in[2];
    const float* text_tab  = (const float*)d_in[3];
    const float* prompt_tab= (const float*)d_in[4];
    const float* output_tab= (const float*)d_in[5];
    const float* sep       = (const float*)d_in[6];
    const float* ln1_g     = (const float*)d_in[7];
    const float* ln1_b     = (const float*)d_in[8];
    const float* qkv_w     = (const float*)d_in[9];
    const float* out_w     = (const float*)d_in[10];
    const float* out_b     = (const float*)d_in[11];
    const float* ln2_g     = (const float*)d_in[12];
    const float* ln2_b     = (const float*)d_in[13];
    const float* ff1_w     = (const float*)d_in[14];
    const float* ff1_b     = (const float*)d_in[15];
    const float* ff2_w     = (const float*)d_in[16];
    const float* ff2_b     = (const float*)d_in[17];
    const float* fc_w      = (const float*)d_in[18];
    const float* fc_b      = (const float*)d_in[19];

    char* ws = (char*)d_ws;
    float*  x    = (float*)(ws);                               // BT*Dn*4   = 29,425,664
    ushort* h    = (ushort*)(ws + 29425664);                   // BT*Dn*2   = 14,712,832
    ushort* qkv  = (ushort*)(ws + 44138496);                   // BT*3Dn*2  = 44,138,496
    ushort* attn = (ushort*)(ws + 88276992);                   // BT*Dn*2   = 14,712,832
    ushort* ff1o = (ushort*)(ws + 102989824);                  // BT*FFn*2  = 58,851,328
    ushort* wT   = (ushort*)(ws + 161841152);                  // weights bf16 [N][K]

    // per-layer packed block (ushort offsets)
    const size_t L_STRIDE = 12582912;        // 3072*1024 + 1024*1024 + 4096*1024 + 1024*4096
    const size_t OFF_QKV = 0, OFF_OUT = 3145728, OFF_FF1 = 4194304, OFF_FF2 = 8388608;
    const size_t upfront_need = 161841152ULL + 2ULL * L_STRIDE * Ln;  // ~463.8 MB
    const bool upfront = ws_size >= upfront_need;
    const int ZL = upfront ? Ln : 1;

    if (upfront) {
        transpose_cast_kernel<<<dim3(48,16,Ln), 256, 0, stream>>>(qkv_w, wT + OFF_QKV, Dn, 3*Dn, (size_t)Dn*3*Dn, L_STRIDE);
        transpose_cast_kernel<<<dim3(16,16,Ln), 256, 0, stream>>>(out_w, wT + OFF_OUT, Dn, Dn,   (size_t)Dn*Dn,   L_STRIDE);
        transpose_cast_kernel<<<dim3(64,16,Ln), 256, 0, stream>>>(ff1_w, wT + OFF_FF1, Dn, FFn,  (size_t)Dn*FFn,  L_STRIDE);
        transpose_cast_kernel<<<dim3(16,64,Ln), 256, 0, stream>>>(ff2_w, wT + OFF_FF2, FFn, Dn,  (size_t)FFn*Dn,  L_STRIDE);
    }

    embed_kernel<<<BT, 256, 0, stream>>>(text_ids, prompt_ids, output_ids,
                                         text_tab, prompt_tab, output_tab, sep, x);

    const int MT = 57; // ceil(7184/128)
    for (int l = 0; l < Ln; l++) {
        ushort* wbase = upfront ? (wT + (size_t)l * L_STRIDE) : wT;
        if (!upfront) {
            transpose_cast_kernel<<<dim3(48,16,1), 256, 0, stream>>>(qkv_w + (size_t)l*Dn*3*Dn, wbase + OFF_QKV, Dn, 3*Dn, 0, 0);
            transpose_cast_kernel<<<dim3(16,16,1), 256, 0, stream>>>(out_w + (size_t)l*Dn*Dn,   wbase + OFF_OUT, Dn, Dn,   0, 0);
            transpose_cast_kernel<<<dim3(64,16,1), 256, 0, stream>>>(ff1_w + (size_t)l*Dn*FFn,  wbase + OFF_FF1, Dn, FFn,  0, 0);
            transpose_cast_kernel<<<dim3(16,64,1), 256, 0, stream>>>(ff2_w + (size_t)l*FFn*Dn,  wbase + OFF_FF2, FFn, Dn,  0, 0);
        }
        ln_kernel<<<BT, 256, 0, stream>>>(x, ln1_g + l*Dn, ln1_b + l*Dn, h);
        gemm_kernel<0><<<dim3(3*Dn/128, MT), 256, 0, stream>>>(
            h, wbase + OFF_QKV, nullptr, nullptr, qkv, BT, 3*Dn, Dn);
        attn_kernel<<<dim3(15, Bn, Hn), 256, 0, stream>>>(qkv, attn);
        gemm_kernel<1><<<dim3(Dn/128, MT), 256, 0, stream>>>(
            attn, wbase + OFF_OUT, out_b + l*Dn, x, x, BT, Dn, Dn);
        ln_kernel<<<BT, 256, 0, stream>>>(x, ln2_g + l*Dn, ln2_b + l*Dn, h);
        gemm_kernel<2><<<dim3(FFn/128, MT), 256, 0, stream>>>(
            h, wbase + OFF_FF1, ff1_b + l*FFn, nullptr, ff1o, BT, FFn, Dn);
        gemm_kernel<1><<<dim3(Dn/128, MT), 256, 0, stream>>>(
            ff1o, wbase + OFF_FF2, ff2_b + l*Dn, x, x, BT, Dn, FFn);
    }

    fc_kernel<<<dim3(Vn/256, Bn), 256, 0, stream>>>(x, fc_w, fc_b, (float*)d_out);
}